// Round 2
// baseline (756.579 us; speedup 1.0000x reference)
//
#include <hip/hip_runtime.h>
#include <stdint.h>

// Problem constants (B=1)
#define H_  12
#define DH_ 64
#define D_  768
#define TD_ 2304      // 3*D
#define E_  128
#define L_  256
#define M_  (E_*L_)   // 32768 rows
#define KDIM_ 768

typedef __bf16 bf16x8 __attribute__((ext_vector_type(8)));
typedef float  f32x4  __attribute__((ext_vector_type(4)));

__device__ __forceinline__ float b2f(unsigned short u) {
    return __uint_as_float(((unsigned int)u) << 16);
}
__device__ __forceinline__ unsigned short f2b(float f) {
    unsigned int u = __float_as_uint(f);
    u += 0x7fffu + ((u >> 16) & 1u);   // RNE
    return (unsigned short)(u >> 16);
}

union frag_u { unsigned short u[8]; bf16x8 v; };

#define GLOBAL_AS(p) ((const __attribute__((address_space(1))) void*)(p))
#define LDS_AS(p)    ((__attribute__((address_space(3))) void*)(p))

// ---------------------------------------------------------------------------
// fp32 -> bf16, 4 elements/thread (n % 4 == 0)
// ---------------------------------------------------------------------------
__global__ __launch_bounds__(256) void cvt4(
    const float4* __restrict__ src, ushort4* __restrict__ dst, int n4)
{
    int i = blockIdx.x * 256 + threadIdx.x;
    if (i < n4) {
        float4 f = src[i];
        ushort4 o;
        o.x = f2b(f.x); o.y = f2b(f.y); o.z = f2b(f.z); o.w = f2b(f.w);
        dst[i] = o;
    }
}

// ---------------------------------------------------------------------------
// C[M,2304](bf16) = A[M,768](bf16) @ Wb[2304,768](bf16)^T + bias(fp32)
// 256x256 tile, 8 waves (2m x 4n), BK=32, ring-4 LDS K-tile buffers (128 KiB),
// depth-3 prefetch with COUNTED s_waitcnt vmcnt(12) across raw s_barriers
// (T3/T4: loads stay in flight across barriers instead of drain-to-0).
// LDS chunk swizzle per 256x32 tile: element (R, colgroup c) stored at chunk
// R*4 + ((c + (R>>1)) & 3) -> frag ds_read_b128 is 2-way (free, measured 0
// conflicts in the 128^2 ancestor). T1 bijective XCD swizzle (1152 % 8 == 0).
// T5 setprio around the 32-MFMA cluster.
// ---------------------------------------------------------------------------
__global__ __launch_bounds__(512, 2) void gemm256(
    const unsigned short* __restrict__ A,
    const unsigned short* __restrict__ Wb,
    const float* __restrict__ bias,
    unsigned short* __restrict__ C)
{
    // 4 ring bufs x (A: 256x32 = 16 KB | B: 256x32 = 16 KB) = 128 KiB
    __shared__ unsigned short LdsU[4 * 16384];
    char* ldsb = (char*)LdsU;

    const int tid  = threadIdx.x;
    const int lane = tid & 63;
    const int w    = tid >> 6;        // 0..7
    const int l15  = lane & 15;
    const int quad = lane >> 4;
    const int wm   = w >> 2;          // 0..1  (m half: 128 rows)
    const int wn   = w & 3;           // 0..3  (n quarter: 64 cols)

    // T1 bijective XCD swizzle: nwg = 9*128 = 1152 = 8 * 144
    const int bid = blockIdx.y * gridDim.x + blockIdx.x;
    const int swz = (bid & 7) * 144 + (bid >> 3);
    const int n_blk = (swz % 9) * 256;
    const int m_blk = (swz / 9) * 256;

    // staging: lane's LDS chunk is fixed; pick the global colgroup that
    // belongs there: cc = ((lane&3) - (R>>1)) & 3, R = w*16 + (lane>>2);
    // w*8 and i*64 terms vanish mod 4 -> cc = ((lane&3) - ((lane>>3)&3)) & 3.
    const int cc   = ((lane & 3) - ((lane >> 3) & 3)) & 3;
    const int rloc = w * 16 + (lane >> 2);          // 0..127
    const unsigned short* gA0 = A  + (size_t)(m_blk + rloc) * KDIM_ + cc * 8;
    const unsigned short* gA1 = gA0 + (size_t)128 * KDIM_;
    const unsigned short* gB0 = Wb + (size_t)(n_blk + rloc) * KDIM_ + cc * 8;
    const unsigned short* gB1 = gB0 + (size_t)128 * KDIM_;

    const int dst0 = (w * 64 + lane) * 16;          // byte offset of own chunk

    // fragment read byte-offsets within a buf (constant over K loop)
    int offA[8], offB[4];
    #pragma unroll
    for (int t = 0; t < 8; t++) {
        int Ra = wm * 128 + t * 16 + l15;
        offA[t] = (Ra * 4 + ((quad + (Ra >> 1)) & 3)) * 16;
    }
    #pragma unroll
    for (int u = 0; u < 4; u++) {
        int Rb = wn * 64 + u * 16 + l15;
        offB[u] = 16384 + (Rb * 4 + ((quad + (Rb >> 1)) & 3)) * 16;
    }

    f32x4 acc[8][4];
    #pragma unroll
    for (int t = 0; t < 8; t++)
        #pragma unroll
        for (int u = 0; u < 4; u++) acc[t][u] = (f32x4){0.f, 0.f, 0.f, 0.f};

#define STAGE(b) do {                                                          \
    char* db_ = ldsb + (b) * 32768;                                            \
    __builtin_amdgcn_global_load_lds(GLOBAL_AS(gA0), LDS_AS(db_ + dst0),         16, 0, 0); \
    __builtin_amdgcn_global_load_lds(GLOBAL_AS(gA1), LDS_AS(db_ + 8192 + dst0),  16, 0, 0); \
    __builtin_amdgcn_global_load_lds(GLOBAL_AS(gB0), LDS_AS(db_ + 16384 + dst0), 16, 0, 0); \
    __builtin_amdgcn_global_load_lds(GLOBAL_AS(gB1), LDS_AS(db_ + 24576 + dst0), 16, 0, 0); \
    gA0 += 32; gA1 += 32; gB0 += 32; gB1 += 32;                                \
} while (0)

#define COMPUTE(b) do {                                                        \
    const char* sb_ = ldsb + (b) * 32768;                                      \
    bf16x8 af[8], bfr[4];                                                      \
    _Pragma("unroll")                                                          \
    for (int t = 0; t < 8; t++)                                                \
        af[t] = *(const bf16x8*)(const void*)(sb_ + offA[t]);                  \
    _Pragma("unroll")                                                          \
    for (int u = 0; u < 4; u++)                                                \
        bfr[u] = *(const bf16x8*)(const void*)(sb_ + offB[u]);                 \
    __builtin_amdgcn_s_setprio(1);                                             \
    _Pragma("unroll")                                                          \
    for (int t = 0; t < 8; t++)                                                \
        _Pragma("unroll")                                                      \
        for (int u = 0; u < 4; u++)                                            \
            acc[t][u] = __builtin_amdgcn_mfma_f32_16x16x32_bf16(               \
                af[t], bfr[u], acc[t][u], 0, 0, 0);                            \
    __builtin_amdgcn_s_setprio(0);                                             \
} while (0)

    // prologue: prefetch K-tiles 0,1,2 (depth 3)
    STAGE(0); STAGE(1); STAGE(2);

    // main: 24 K-tiles of BK=32.  At iter kt: issue stage kt+3, then wait
    // until only the newest 3 stages (12 loads) are in flight -> kt landed.
    for (int kt = 0; kt < 21; kt++) {
        STAGE((kt + 3) & 3);
        asm volatile("s_waitcnt vmcnt(12)" ::: "memory");
        asm volatile("s_barrier" ::: "memory");
        COMPUTE(kt & 3);
        asm volatile("s_barrier" ::: "memory");
    }
    // tail: kt = 21, 22, 23 — no more stages; drain 8 -> 4 -> 0.
    asm volatile("s_waitcnt vmcnt(8)" ::: "memory");
    asm volatile("s_barrier" ::: "memory");
    COMPUTE(1);
    asm volatile("s_waitcnt vmcnt(4)" ::: "memory");
    asm volatile("s_barrier" ::: "memory");
    COMPUTE(2);
    asm volatile("s_waitcnt vmcnt(0)" ::: "memory");
    asm volatile("s_barrier" ::: "memory");
    COMPUTE(3);

#undef STAGE
#undef COMPUTE

    // epilogue: C[row = quad*4 + r][col = l15] per 16x16 frag (verified layout)
    #pragma unroll
    for (int u = 0; u < 4; u++) {
        int col = n_blk + wn * 64 + u * 16 + l15;
        float bi = bias[col];
        #pragma unroll
        for (int t = 0; t < 8; t++) {
            int rbase = m_blk + wm * 128 + t * 16 + quad * 4;
            #pragma unroll
            for (int r = 0; r < 4; r++)
                C[(size_t)(rbase + r) * TD_ + col] = f2b(acc[t][u][r] + bi);
        }
    }
}

// ---------------------------------------------------------------------------
// MFMA attention. One (outer,h) per block, 4 waves, 256 threads.
// MODE 0: row attn (n=256 over L);  MODE 1: col attn (n=128 over E)
// ---------------------------------------------------------------------------
template<int MODE>
__global__ __launch_bounds__(256) void attn_mfma(
    const unsigned short* __restrict__ qkv,
    unsigned short* __restrict__ attnout,
    const int* __restrict__ mask)
{
    constexpr int N  = (MODE == 0) ? L_ : E_;
    constexpr int NT = N / 16;
    constexpr int KS = N / 32;
    constexpr int HALVES = N / 128;
    constexpr int MT = N / 64;

    __shared__ unsigned short VtS[64 * N];
    __shared__ unsigned short Ps[4][16][136];

    const int tid  = threadIdx.x;
    const int lane = tid & 63;
    const int w    = tid >> 6;
    const int quad = lane >> 4;
    const int l15  = lane & 15;
    const int hh    = blockIdx.x % H_;
    const int outer = blockIdx.x / H_;

    size_t base, stride, obase, ostride; int mbase, mstride;
    if (MODE == 0) {
        stride = TD_;              base = (size_t)outer * L_ * TD_;
        obase  = (size_t)outer * L_ * D_;  ostride = D_;
        mbase  = outer * L_;       mstride = 1;
    } else {
        stride = (size_t)L_ * TD_; base = (size_t)outer * TD_;
        obase  = (size_t)outer * D_;       ostride = (size_t)L_ * D_;
        mbase  = outer;            mstride = L_;
    }
    const unsigned short* Qg = qkv + base + hh * DH_;
    const unsigned short* Kg = Qg + D_;
    const unsigned short* Vg = Qg + 2 * D_;

    for (int c = tid; c < 4 * KS * 64; c += 256) {
        int tile = c >> 6, lc = c & 63;
        int qd = lc >> 4, fl = lc & 15;
        int dt = tile / KS, kt = tile % KS;
        int jb = kt * 32 + qd * 8;
        int d  = dt * 16 + fl;
        frag_u tmp;
        #pragma unroll
        for (int jj = 0; jj < 8; jj++)
            tmp.u[jj] = Vg[(size_t)(jb + jj) * stride + d];
        *(bf16x8*)(void*)&VtS[c * 8] = tmp.v;
    }

    float negreg[NT];
    #pragma unroll
    for (int nt = 0; nt < NT; nt++)
        negreg[nt] = mask[mbase + (nt * 16 + l15) * mstride] ? -10000.0f : 0.0f;

    __syncthreads();

    for (int mt = 0; mt < MT; mt++) {
        int m0 = (w * MT + mt) * 16;

        bf16x8 aq0 = *(const bf16x8*)(const void*)&Qg[(size_t)(m0 + l15) * stride + quad * 8];
        bf16x8 aq1 = *(const bf16x8*)(const void*)&Qg[(size_t)(m0 + l15) * stride + 32 + quad * 8];

        f32x4 sc[NT];
        #pragma unroll
        for (int nt = 0; nt < NT; nt++) sc[nt] = (f32x4){0.f,0.f,0.f,0.f};
        #pragma unroll
        for (int nt = 0; nt < NT; nt++) {
            bf16x8 bk0 = *(const bf16x8*)(const void*)&Kg[(size_t)(nt*16 + l15) * stride + quad * 8];
            bf16x8 bk1 = *(const bf16x8*)(const void*)&Kg[(size_t)(nt*16 + l15) * stride + 32 + quad * 8];
            sc[nt] = __builtin_amdgcn_mfma_f32_16x16x32_bf16(aq0, bk0, sc[nt], 0, 0, 0);
            sc[nt] = __builtin_amdgcn_mfma_f32_16x16x32_bf16(aq1, bk1, sc[nt], 0, 0, 0);
        }

        float mx[4] = {-1e30f, -1e30f, -1e30f, -1e30f};
        #pragma unroll
        for (int nt = 0; nt < NT; nt++)
            #pragma unroll
            for (int r = 0; r < 4; r++) {
                float s = sc[nt][r] * 0.125f + negreg[nt];
                sc[nt][r] = s;
                mx[r] = fmaxf(mx[r], s);
            }
        #pragma unroll
        for (int r = 0; r < 4; r++) {
            mx[r] = fmaxf(mx[r], __shfl_xor(mx[r], 1));
            mx[r] = fmaxf(mx[r], __shfl_xor(mx[r], 2));
            mx[r] = fmaxf(mx[r], __shfl_xor(mx[r], 4));
            mx[r] = fmaxf(mx[r], __shfl_xor(mx[r], 8));
        }
        float sum[4] = {0.f, 0.f, 0.f, 0.f};
        #pragma unroll
        for (int nt = 0; nt < NT; nt++)
            #pragma unroll
            for (int r = 0; r < 4; r++) {
                float p = __expf(sc[nt][r] - mx[r]);
                sc[nt][r] = p;
                sum[r] += p;
            }
        #pragma unroll
        for (int r = 0; r < 4; r++) {
            sum[r] += __shfl_xor(sum[r], 1);
            sum[r] += __shfl_xor(sum[r], 2);
            sum[r] += __shfl_xor(sum[r], 4);
            sum[r] += __shfl_xor(sum[r], 8);
        }

        f32x4 oacc[4];
        #pragma unroll
        for (int dt = 0; dt < 4; dt++) oacc[dt] = (f32x4){0.f,0.f,0.f,0.f};

        #pragma unroll
        for (int h2 = 0; h2 < HALVES; h2++) {
            #pragma unroll
            for (int t = 0; t < 8; t++)
                #pragma unroll
                for (int r = 0; r < 4; r++)
                    Ps[w][quad * 4 + r][t * 16 + l15] = f2b(sc[h2 * 8 + t][r]);
            #pragma unroll
            for (int kt = 0; kt < 4; kt++) {
                bf16x8 ap = *(const bf16x8*)(const void*)&Ps[w][l15][kt * 32 + quad * 8];
                #pragma unroll
                for (int dt = 0; dt < 4; dt++) {
                    bf16x8 bv = *(const bf16x8*)(const void*)
                        &VtS[((dt * KS + h2 * 4 + kt) * 64 + lane) * 8];
                    oacc[dt] = __builtin_amdgcn_mfma_f32_16x16x32_bf16(ap, bv, oacc[dt], 0, 0, 0);
                }
            }
        }

        float inv[4];
        #pragma unroll
        for (int r = 0; r < 4; r++) inv[r] = 1.0f / sum[r];
        #pragma unroll
        for (int dt = 0; dt < 4; dt++)
            #pragma unroll
            for (int r = 0; r < 4; r++) {
                size_t oaddr = obase + (size_t)(m0 + quad * 4 + r) * ostride
                             + hh * DH_ + dt * 16 + l15;
                attnout[oaddr] = f2b(oacc[dt][r] * inv[r]);
            }
    }
}

// ---------------------------------------------------------------------------
// out = LayerNorm(x + r) * g + beta — one wave per row.
// XBF16: residual input dtype; OBF16: output dtype.
// ---------------------------------------------------------------------------
template<int XBF16, int OBF16>
__global__ __launch_bounds__(256) void add_ln(
    const void* __restrict__ xp,
    const unsigned short* __restrict__ r,
    const float* __restrict__ g,
    const float* __restrict__ bta,
    void* __restrict__ outp)
{
    int row  = blockIdx.x * 4 + (threadIdx.x >> 6);
    int lane = threadIdx.x & 63;
    size_t off = (size_t)row * D_;
    const float* xf = (const float*)xp;
    const unsigned short* xb = (const unsigned short*)xp;
    float v[12];
    float sum = 0.f;
    #pragma unroll
    for (int j = 0; j < 12; j++) {
        int c = j * 64 + lane;
        float xv = XBF16 ? b2f(xb[off + c]) : xf[off + c];
        v[j] = xv + b2f(r[off + c]);
        sum += v[j];
    }
    for (int o = 32; o; o >>= 1) sum += __shfl_xor(sum, o);
    float mu = sum * (1.0f / 768.0f);
    float s2 = 0.f;
    #pragma unroll
    for (int j = 0; j < 12; j++) { float d = v[j] - mu; s2 = fmaf(d, d, s2); }
    for (int o = 32; o; o >>= 1) s2 += __shfl_xor(s2, o);
    float rs = rsqrtf(s2 * (1.0f / 768.0f) + 1e-5f);
    #pragma unroll
    for (int j = 0; j < 12; j++) {
        int c = j * 64 + lane;
        float y = (v[j] - mu) * rs * g[c] + bta[c];
        if (OBF16) ((unsigned short*)outp)[off + c] = f2b(y);
        else       ((float*)outp)[off + c] = y;
    }
}

// ---------------------------------------------------------------------------
extern "C" void kernel_launch(void* const* d_in, const int* in_sizes, int n_in,
                              void* d_out, int out_size, void* d_ws, size_t ws_size,
                              hipStream_t stream)
{
    const float* x     = (const float*)d_in[0];
    const float* w_row = (const float*)d_in[1];
    const float* b_row = (const float*)d_in[2];
    const float* w_col = (const float*)d_in[3];
    const float* b_col = (const float*)d_in[4];
    const float* g1    = (const float*)d_in[5];
    const float* be1   = (const float*)d_in[6];
    const float* g2    = (const float*)d_in[7];
    const float* be2   = (const float*)d_in[8];
    const int*   mask  = (const int*)d_in[9];
    float* out = (float*)d_out;

    char* ws = (char*)d_ws;
    size_t o = 0;
    unsigned short* qkv   = (unsigned short*)(ws + o); o += (size_t)M_ * TD_ * 2;    // 151 MB
    unsigned short* attn  = (unsigned short*)(ws + o); o += (size_t)M_ * D_ * 2;     // 48 MB (aliases xb)
    unsigned short* out1b = (unsigned short*)(ws + o); o += (size_t)M_ * D_ * 2;     // 48 MB
    unsigned short* wbr   = (unsigned short*)(ws + o); o += (size_t)TD_ * KDIM_ * 2; // 3.4 MB
    unsigned short* wbc   = (unsigned short*)(ws + o);                               // 3.4 MB
    unsigned short* xb    = attn;   // safe alias: xb consumed by gemm1 before attn<0> writes

    int wn4 = TD_ * KDIM_ / 4;
    int xn4 = M_ * D_ / 4;
    cvt4<<<(wn4 + 255) / 256, 256, 0, stream>>>((const float4*)w_row, (ushort4*)wbr, wn4);
    cvt4<<<(wn4 + 255) / 256, 256, 0, stream>>>((const float4*)w_col, (ushort4*)wbc, wn4);
    cvt4<<<(xn4 + 255) / 256, 256, 0, stream>>>((const float4*)x, (ushort4*)xb, xn4);

    dim3 gg(TD_ / 256, M_ / 256);   // 9 x 128 = 1152 blocks

    // ---- row attention ----
    gemm256<<<gg, 512, 0, stream>>>(xb, wbr, b_row, qkv);
    attn_mfma<0><<<E_ * H_, 256, 0, stream>>>(qkv, attn, mask);
    add_ln<0, 1><<<M_ / 4, 256, 0, stream>>>(x, attn, g1, be1, out1b);

    // ---- column attention ----
    gemm256<<<gg, 512, 0, stream>>>(out1b, wbc, b_col, qkv);
    attn_mfma<1><<<L_ * H_, 256, 0, stream>>>(qkv, attn, mask);
    add_ln<1, 0><<<M_ / 4, 256, 0, stream>>>(out1b, attn, g2, be2, out);
}

// Round 3
// 737.024 us; speedup vs baseline: 1.0265x; 1.0265x over previous
//
#include <hip/hip_runtime.h>
#include <stdint.h>

// Problem constants (B=1)
#define H_  12
#define DH_ 64
#define D_  768
#define TD_ 2304      // 3*D
#define E_  128
#define L_  256
#define M_  (E_*L_)   // 32768 rows
#define KDIM_ 768

typedef __bf16 bf16x8 __attribute__((ext_vector_type(8)));
typedef float  f32x4  __attribute__((ext_vector_type(4)));

__device__ __forceinline__ float b2f(unsigned short u) {
    return __uint_as_float(((unsigned int)u) << 16);
}
__device__ __forceinline__ unsigned short f2b(float f) {
    unsigned int u = __float_as_uint(f);
    u += 0x7fffu + ((u >> 16) & 1u);   // RNE
    return (unsigned short)(u >> 16);
}

union frag_u { unsigned short u[8]; bf16x8 v; };

#define GLOBAL_AS(p) ((const __attribute__((address_space(1))) void*)(p))
#define LDS_AS(p)    ((__attribute__((address_space(3))) void*)(p))

// ---------------------------------------------------------------------------
// fp32 -> bf16, 4 elements/thread (n % 4 == 0)
// ---------------------------------------------------------------------------
__global__ __launch_bounds__(256) void cvt4(
    const float4* __restrict__ src, ushort4* __restrict__ dst, int n4)
{
    int i = blockIdx.x * 256 + threadIdx.x;
    if (i < n4) {
        float4 f = src[i];
        ushort4 o;
        o.x = f2b(f.x); o.y = f2b(f.y); o.z = f2b(f.z); o.w = f2b(f.w);
        dst[i] = o;
    }
}

// ---------------------------------------------------------------------------
// C[M,2304](bf16) = A[M,768](bf16) @ Wb[2304,768](bf16)^T + bias(fp32)
// 256x256 tile, 8 waves (2m x 4n), BK=32, ring-4 LDS K-tile slots (128 KiB),
// depth-3 prefetch.  m201-style PHASE SPLIT: each K-tile = 2 phases of
// 16 MFMA; per phase {ds_read (8|4) | 2 stage-loads | s_barrier | lgkm(0) |
// setprio | 16 MFMA | s_barrier}.  vmcnt gate of 8 ONCE per tile (never 0
// in main loop).  Ring-4 makes every stage target a provably-dead slot:
// stage issue is after the gate barrier, which is after all reads of that
// slot (tile kt stages slot (kt+3)&3 = slot of tile kt-1, fully consumed).
// LDS chunk swizzle per 256x32 tile unchanged (measured 0 conflicts).
// T1 bijective XCD swizzle (1152 % 8 == 0).  T5 setprio around MFMA.
// ---------------------------------------------------------------------------
__global__ __launch_bounds__(512, 2) void gemm256(
    const unsigned short* __restrict__ A,
    const unsigned short* __restrict__ Wb,
    const float* __restrict__ bias,
    unsigned short* __restrict__ C)
{
    // 4 ring slots x (A: 256x32 = 16 KB | B: 256x32 = 16 KB) = 128 KiB
    __shared__ unsigned short LdsU[4 * 16384];
    char* ldsb = (char*)LdsU;

    const int tid  = threadIdx.x;
    const int lane = tid & 63;
    const int w    = tid >> 6;        // 0..7
    const int l15  = lane & 15;
    const int quad = lane >> 4;
    const int wm   = w >> 2;          // 0..1  (m half: 128 rows)
    const int wn   = w & 3;           // 0..3  (n quarter: 64 cols)

    // T1 bijective XCD swizzle: nwg = 9*128 = 1152 = 8 * 144
    const int bid = blockIdx.y * gridDim.x + blockIdx.x;
    const int swz = (bid & 7) * 144 + (bid >> 3);
    const int n_blk = (swz % 9) * 256;
    const int m_blk = (swz / 9) * 256;

    // staging: lane's LDS chunk is fixed; pick the global colgroup that
    // belongs there: cc = ((lane&3) - (R>>1)) & 3, R = w*16 + (lane>>2);
    // w*8 and i*64 terms vanish mod 4 -> cc = ((lane&3) - ((lane>>3)&3)) & 3.
    const int cc   = ((lane & 3) - ((lane >> 3) & 3)) & 3;
    const int rloc = w * 16 + (lane >> 2);          // 0..127
    const unsigned short* gA0 = A  + (size_t)(m_blk + rloc) * KDIM_ + cc * 8;
    const unsigned short* gA1 = gA0 + (size_t)128 * KDIM_;
    const unsigned short* gB0 = Wb + (size_t)(n_blk + rloc) * KDIM_ + cc * 8;
    const unsigned short* gB1 = gB0 + (size_t)128 * KDIM_;

    const int dst0 = (w * 64 + lane) * 16;          // byte offset of own chunk

    // fragment read byte-offsets within a slot (constant over K loop)
    int offA[8], offB[4];
    #pragma unroll
    for (int t = 0; t < 8; t++) {
        int Ra = wm * 128 + t * 16 + l15;
        offA[t] = (Ra * 4 + ((quad + (Ra >> 1)) & 3)) * 16;
    }
    #pragma unroll
    for (int u = 0; u < 4; u++) {
        int Rb = wn * 64 + u * 16 + l15;
        offB[u] = 16384 + (Rb * 4 + ((quad + (Rb >> 1)) & 3)) * 16;
    }

    f32x4 acc[8][4];
    #pragma unroll
    for (int t = 0; t < 8; t++)
        #pragma unroll
        for (int u = 0; u < 4; u++) acc[t][u] = (f32x4){0.f, 0.f, 0.f, 0.f};

#define STAGE_A(b) do {                                                        \
    char* db_ = ldsb + (b) * 32768;                                            \
    __builtin_amdgcn_global_load_lds(GLOBAL_AS(gA0), LDS_AS(db_ + dst0),        16, 0, 0); \
    __builtin_amdgcn_global_load_lds(GLOBAL_AS(gA1), LDS_AS(db_ + 8192 + dst0), 16, 0, 0); \
    gA0 += 32; gA1 += 32;                                                      \
} while (0)

#define STAGE_B(b) do {                                                        \
    char* db_ = ldsb + (b) * 32768;                                            \
    __builtin_amdgcn_global_load_lds(GLOBAL_AS(gB0), LDS_AS(db_ + 16384 + dst0), 16, 0, 0); \
    __builtin_amdgcn_global_load_lds(GLOBAL_AS(gB1), LDS_AS(db_ + 24576 + dst0), 16, 0, 0); \
    gB0 += 32; gB1 += 32;                                                      \
} while (0)

// One K-tile from slot b: 2 phases of 16 MFMA.
// Phase 0: m-frags 0-3 x all B (reads 4 A + 4 B; stages next A half-pair)
// Phase 1: m-frags 4-7 (B held in regs; reads 4 A; stages next B half-pair)
#define TILE(b, DO_STAGE) do {                                                 \
    const char* sb_ = ldsb + (b) * 32768;                                      \
    bf16x8 af[4], ag[4], bfr[4];                                               \
    /* ---- phase 0 ---- */                                                    \
    _Pragma("unroll")                                                          \
    for (int t = 0; t < 4; t++)                                                \
        af[t]  = *(const bf16x8*)(const void*)(sb_ + offA[t]);                 \
    _Pragma("unroll")                                                          \
    for (int u = 0; u < 4; u++)                                                \
        bfr[u] = *(const bf16x8*)(const void*)(sb_ + offB[u]);                 \
    if (DO_STAGE) { STAGE_A(((b) + 3) & 3); }                                  \
    asm volatile("s_barrier" ::: "memory");                                    \
    asm volatile("s_waitcnt lgkmcnt(0)" ::: "memory");                         \
    __builtin_amdgcn_sched_barrier(0);                                         \
    __builtin_amdgcn_s_setprio(1);                                             \
    _Pragma("unroll")                                                          \
    for (int t = 0; t < 4; t++)                                                \
        _Pragma("unroll")                                                      \
        for (int u = 0; u < 4; u++)                                            \
            acc[t][u] = __builtin_amdgcn_mfma_f32_16x16x32_bf16(               \
                af[t], bfr[u], acc[t][u], 0, 0, 0);                            \
    __builtin_amdgcn_s_setprio(0);                                             \
    asm volatile("s_barrier" ::: "memory");                                    \
    /* ---- phase 1 ---- */                                                    \
    _Pragma("unroll")                                                          \
    for (int t = 0; t < 4; t++)                                                \
        ag[t] = *(const bf16x8*)(const void*)(sb_ + offA[4 + t]);              \
    if (DO_STAGE) { STAGE_B(((b) + 3) & 3); }                                  \
    asm volatile("s_barrier" ::: "memory");                                    \
    asm volatile("s_waitcnt lgkmcnt(0)" ::: "memory");                         \
    __builtin_amdgcn_sched_barrier(0);                                         \
    __builtin_amdgcn_s_setprio(1);                                             \
    _Pragma("unroll")                                                          \
    for (int t = 0; t < 4; t++)                                                \
        _Pragma("unroll")                                                      \
        for (int u = 0; u < 4; u++)                                            \
            acc[4 + t][u] = __builtin_amdgcn_mfma_f32_16x16x32_bf16(           \
                ag[t], bfr[u], acc[4 + t][u], 0, 0, 0);                        \
    __builtin_amdgcn_s_setprio(0);                                             \
} while (0)

    // prologue: prefetch K-tiles 0,1,2 into slots 0,1,2 (depth 3; 12 loads)
    STAGE_A(0); STAGE_B(0);
    STAGE_A(1); STAGE_B(1);
    STAGE_A(2); STAGE_B(2);

    // main: 24 K-tiles of BK=32.  Gate vmcnt(8): tiles kt+1,kt+2 (8 loads)
    // may remain in flight -> tile kt fully landed.  Gate barrier makes the
    // landing visible to all waves before any wave reads the slot.
    for (int kt = 0; kt < 21; ++kt) {
        asm volatile("s_waitcnt vmcnt(8)" ::: "memory");
        asm volatile("s_barrier" ::: "memory");
        TILE(kt & 3, 1);
    }
    // tail: tiles 21,22,23 — no more staging; gates 8 -> 4 -> 0.
    asm volatile("s_waitcnt vmcnt(8)" ::: "memory");
    asm volatile("s_barrier" ::: "memory");
    TILE(1, 0);
    asm volatile("s_waitcnt vmcnt(4)" ::: "memory");
    asm volatile("s_barrier" ::: "memory");
    TILE(2, 0);
    asm volatile("s_waitcnt vmcnt(0)" ::: "memory");
    asm volatile("s_barrier" ::: "memory");
    TILE(3, 0);

#undef TILE
#undef STAGE_A
#undef STAGE_B

    // epilogue: C[row = quad*4 + r][col = l15] per 16x16 frag (verified layout)
    #pragma unroll
    for (int u = 0; u < 4; u++) {
        int col = n_blk + wn * 64 + u * 16 + l15;
        float bi = bias[col];
        #pragma unroll
        for (int t = 0; t < 8; t++) {
            int rbase = m_blk + wm * 128 + t * 16 + quad * 4;
            #pragma unroll
            for (int r = 0; r < 4; r++)
                C[(size_t)(rbase + r) * TD_ + col] = f2b(acc[t][u][r] + bi);
        }
    }
}

// ---------------------------------------------------------------------------
// MFMA attention. One (outer,h) per block, 4 waves, 256 threads.
// MODE 0: row attn (n=256 over L);  MODE 1: col attn (n=128 over E)
// ---------------------------------------------------------------------------
template<int MODE>
__global__ __launch_bounds__(256) void attn_mfma(
    const unsigned short* __restrict__ qkv,
    unsigned short* __restrict__ attnout,
    const int* __restrict__ mask)
{
    constexpr int N  = (MODE == 0) ? L_ : E_;
    constexpr int NT = N / 16;
    constexpr int KS = N / 32;
    constexpr int HALVES = N / 128;
    constexpr int MT = N / 64;

    __shared__ unsigned short VtS[64 * N];
    __shared__ unsigned short Ps[4][16][136];

    const int tid  = threadIdx.x;
    const int lane = tid & 63;
    const int w    = tid >> 6;
    const int quad = lane >> 4;
    const int l15  = lane & 15;
    const int hh    = blockIdx.x % H_;
    const int outer = blockIdx.x / H_;

    size_t base, stride, obase, ostride; int mbase, mstride;
    if (MODE == 0) {
        stride = TD_;              base = (size_t)outer * L_ * TD_;
        obase  = (size_t)outer * L_ * D_;  ostride = D_;
        mbase  = outer * L_;       mstride = 1;
    } else {
        stride = (size_t)L_ * TD_; base = (size_t)outer * TD_;
        obase  = (size_t)outer * D_;       ostride = (size_t)L_ * D_;
        mbase  = outer;            mstride = L_;
    }
    const unsigned short* Qg = qkv + base + hh * DH_;
    const unsigned short* Kg = Qg + D_;
    const unsigned short* Vg = Qg + 2 * D_;

    for (int c = tid; c < 4 * KS * 64; c += 256) {
        int tile = c >> 6, lc = c & 63;
        int qd = lc >> 4, fl = lc & 15;
        int dt = tile / KS, kt = tile % KS;
        int jb = kt * 32 + qd * 8;
        int d  = dt * 16 + fl;
        frag_u tmp;
        #pragma unroll
        for (int jj = 0; jj < 8; jj++)
            tmp.u[jj] = Vg[(size_t)(jb + jj) * stride + d];
        *(bf16x8*)(void*)&VtS[c * 8] = tmp.v;
    }

    float negreg[NT];
    #pragma unroll
    for (int nt = 0; nt < NT; nt++)
        negreg[nt] = mask[mbase + (nt * 16 + l15) * mstride] ? -10000.0f : 0.0f;

    __syncthreads();

    for (int mt = 0; mt < MT; mt++) {
        int m0 = (w * MT + mt) * 16;

        bf16x8 aq0 = *(const bf16x8*)(const void*)&Qg[(size_t)(m0 + l15) * stride + quad * 8];
        bf16x8 aq1 = *(const bf16x8*)(const void*)&Qg[(size_t)(m0 + l15) * stride + 32 + quad * 8];

        f32x4 sc[NT];
        #pragma unroll
        for (int nt = 0; nt < NT; nt++) sc[nt] = (f32x4){0.f,0.f,0.f,0.f};
        #pragma unroll
        for (int nt = 0; nt < NT; nt++) {
            bf16x8 bk0 = *(const bf16x8*)(const void*)&Kg[(size_t)(nt*16 + l15) * stride + quad * 8];
            bf16x8 bk1 = *(const bf16x8*)(const void*)&Kg[(size_t)(nt*16 + l15) * stride + 32 + quad * 8];
            sc[nt] = __builtin_amdgcn_mfma_f32_16x16x32_bf16(aq0, bk0, sc[nt], 0, 0, 0);
            sc[nt] = __builtin_amdgcn_mfma_f32_16x16x32_bf16(aq1, bk1, sc[nt], 0, 0, 0);
        }

        float mx[4] = {-1e30f, -1e30f, -1e30f, -1e30f};
        #pragma unroll
        for (int nt = 0; nt < NT; nt++)
            #pragma unroll
            for (int r = 0; r < 4; r++) {
                float s = sc[nt][r] * 0.125f + negreg[nt];
                sc[nt][r] = s;
                mx[r] = fmaxf(mx[r], s);
            }
        #pragma unroll
        for (int r = 0; r < 4; r++) {
            mx[r] = fmaxf(mx[r], __shfl_xor(mx[r], 1));
            mx[r] = fmaxf(mx[r], __shfl_xor(mx[r], 2));
            mx[r] = fmaxf(mx[r], __shfl_xor(mx[r], 4));
            mx[r] = fmaxf(mx[r], __shfl_xor(mx[r], 8));
        }
        float sum[4] = {0.f, 0.f, 0.f, 0.f};
        #pragma unroll
        for (int nt = 0; nt < NT; nt++)
            #pragma unroll
            for (int r = 0; r < 4; r++) {
                float p = __expf(sc[nt][r] - mx[r]);
                sc[nt][r] = p;
                sum[r] += p;
            }
        #pragma unroll
        for (int r = 0; r < 4; r++) {
            sum[r] += __shfl_xor(sum[r], 1);
            sum[r] += __shfl_xor(sum[r], 2);
            sum[r] += __shfl_xor(sum[r], 4);
            sum[r] += __shfl_xor(sum[r], 8);
        }

        f32x4 oacc[4];
        #pragma unroll
        for (int dt = 0; dt < 4; dt++) oacc[dt] = (f32x4){0.f,0.f,0.f,0.f};

        #pragma unroll
        for (int h2 = 0; h2 < HALVES; h2++) {
            #pragma unroll
            for (int t = 0; t < 8; t++)
                #pragma unroll
                for (int r = 0; r < 4; r++)
                    Ps[w][quad * 4 + r][t * 16 + l15] = f2b(sc[h2 * 8 + t][r]);
            #pragma unroll
            for (int kt = 0; kt < 4; kt++) {
                bf16x8 ap = *(const bf16x8*)(const void*)&Ps[w][l15][kt * 32 + quad * 8];
                #pragma unroll
                for (int dt = 0; dt < 4; dt++) {
                    bf16x8 bv = *(const bf16x8*)(const void*)
                        &VtS[((dt * KS + h2 * 4 + kt) * 64 + lane) * 8];
                    oacc[dt] = __builtin_amdgcn_mfma_f32_16x16x32_bf16(ap, bv, oacc[dt], 0, 0, 0);
                }
            }
        }

        float inv[4];
        #pragma unroll
        for (int r = 0; r < 4; r++) inv[r] = 1.0f / sum[r];
        #pragma unroll
        for (int dt = 0; dt < 4; dt++)
            #pragma unroll
            for (int r = 0; r < 4; r++) {
                size_t oaddr = obase + (size_t)(m0 + quad * 4 + r) * ostride
                             + hh * DH_ + dt * 16 + l15;
                attnout[oaddr] = f2b(oacc[dt][r] * inv[r]);
            }
    }
}

// ---------------------------------------------------------------------------
// out = LayerNorm(x + r) * g + beta — one wave per row.
// XBF16: residual input dtype; OBF16: output dtype.
// ---------------------------------------------------------------------------
template<int XBF16, int OBF16>
__global__ __launch_bounds__(256) void add_ln(
    const void* __restrict__ xp,
    const unsigned short* __restrict__ r,
    const float* __restrict__ g,
    const float* __restrict__ bta,
    void* __restrict__ outp)
{
    int row  = blockIdx.x * 4 + (threadIdx.x >> 6);
    int lane = threadIdx.x & 63;
    size_t off = (size_t)row * D_;
    const float* xf = (const float*)xp;
    const unsigned short* xb = (const unsigned short*)xp;
    float v[12];
    float sum = 0.f;
    #pragma unroll
    for (int j = 0; j < 12; j++) {
        int c = j * 64 + lane;
        float xv = XBF16 ? b2f(xb[off + c]) : xf[off + c];
        v[j] = xv + b2f(r[off + c]);
        sum += v[j];
    }
    for (int o = 32; o; o >>= 1) sum += __shfl_xor(sum, o);
    float mu = sum * (1.0f / 768.0f);
    float s2 = 0.f;
    #pragma unroll
    for (int j = 0; j < 12; j++) { float d = v[j] - mu; s2 = fmaf(d, d, s2); }
    for (int o = 32; o; o >>= 1) s2 += __shfl_xor(s2, o);
    float rs = rsqrtf(s2 * (1.0f / 768.0f) + 1e-5f);
    #pragma unroll
    for (int j = 0; j < 12; j++) {
        int c = j * 64 + lane;
        float y = (v[j] - mu) * rs * g[c] + bta[c];
        if (OBF16) ((unsigned short*)outp)[off + c] = f2b(y);
        else       ((float*)outp)[off + c] = y;
    }
}

// ---------------------------------------------------------------------------
extern "C" void kernel_launch(void* const* d_in, const int* in_sizes, int n_in,
                              void* d_out, int out_size, void* d_ws, size_t ws_size,
                              hipStream_t stream)
{
    const float* x     = (const float*)d_in[0];
    const float* w_row = (const float*)d_in[1];
    const float* b_row = (const float*)d_in[2];
    const float* w_col = (const float*)d_in[3];
    const float* b_col = (const float*)d_in[4];
    const float* g1    = (const float*)d_in[5];
    const float* be1   = (const float*)d_in[6];
    const float* g2    = (const float*)d_in[7];
    const float* be2   = (const float*)d_in[8];
    const int*   mask  = (const int*)d_in[9];
    float* out = (float*)d_out;

    char* ws = (char*)d_ws;
    size_t o = 0;
    unsigned short* qkv   = (unsigned short*)(ws + o); o += (size_t)M_ * TD_ * 2;    // 151 MB
    unsigned short* attn  = (unsigned short*)(ws + o); o += (size_t)M_ * D_ * 2;     // 48 MB (aliases xb)
    unsigned short* out1b = (unsigned short*)(ws + o); o += (size_t)M_ * D_ * 2;     // 48 MB
    unsigned short* wbr   = (unsigned short*)(ws + o); o += (size_t)TD_ * KDIM_ * 2; // 3.4 MB
    unsigned short* wbc   = (unsigned short*)(ws + o);                               // 3.4 MB
    unsigned short* xb    = attn;   // safe alias: xb consumed by gemm1 before attn<0> writes

    int wn4 = TD_ * KDIM_ / 4;
    int xn4 = M_ * D_ / 4;
    cvt4<<<(wn4 + 255) / 256, 256, 0, stream>>>((const float4*)w_row, (ushort4*)wbr, wn4);
    cvt4<<<(wn4 + 255) / 256, 256, 0, stream>>>((const float4*)w_col, (ushort4*)wbc, wn4);
    cvt4<<<(xn4 + 255) / 256, 256, 0, stream>>>((const float4*)x, (ushort4*)xb, xn4);

    dim3 gg(TD_ / 256, M_ / 256);   // 9 x 128 = 1152 blocks

    // ---- row attention ----
    gemm256<<<gg, 512, 0, stream>>>(xb, wbr, b_row, qkv);
    attn_mfma<0><<<E_ * H_, 256, 0, stream>>>(qkv, attn, mask);
    add_ln<0, 1><<<M_ / 4, 256, 0, stream>>>(x, attn, g1, be1, out1b);

    // ---- column attention ----
    gemm256<<<gg, 512, 0, stream>>>(out1b, wbc, b_col, qkv);
    attn_mfma<1><<<L_ * H_, 256, 0, stream>>>(qkv, attn, mask);
    add_ln<1, 0><<<M_ / 4, 256, 0, stream>>>(out1b, attn, g2, be2, out);
}

// Round 4
// 723.754 us; speedup vs baseline: 1.0454x; 1.0183x over previous
//
#include <hip/hip_runtime.h>
#include <stdint.h>

// Problem constants (B=1)
#define H_  12
#define DH_ 64
#define D_  768
#define TD_ 2304      // 3*D
#define E_  128
#define L_  256
#define M_  (E_*L_)   // 32768 rows
#define KDIM_ 768

typedef __bf16 bf16x8 __attribute__((ext_vector_type(8)));
typedef float  f32x4  __attribute__((ext_vector_type(4)));

__device__ __forceinline__ float b2f(unsigned short u) {
    return __uint_as_float(((unsigned int)u) << 16);
}
__device__ __forceinline__ unsigned short f2b(float f) {
    unsigned int u = __float_as_uint(f);
    u += 0x7fffu + ((u >> 16) & 1u);   // RNE
    return (unsigned short)(u >> 16);
}

union frag_u { unsigned short u[8]; bf16x8 v; };

#define GLOBAL_AS(p) ((const __attribute__((address_space(1))) void*)(p))
#define LDS_AS(p)    ((__attribute__((address_space(3))) void*)(p))

// ---------------------------------------------------------------------------
// fp32 -> bf16, 4 elements/thread (n % 4 == 0)
// ---------------------------------------------------------------------------
__global__ __launch_bounds__(256) void cvt4(
    const float4* __restrict__ src, ushort4* __restrict__ dst, int n4)
{
    int i = blockIdx.x * 256 + threadIdx.x;
    if (i < n4) {
        float4 f = src[i];
        ushort4 o;
        o.x = f2b(f.x); o.y = f2b(f.y); o.z = f2b(f.z); o.w = f2b(f.w);
        dst[i] = o;
    }
}

// ---------------------------------------------------------------------------
// C[M,2304](bf16) = A[M,768](bf16) @ Wb[2304,768](bf16)^T + bias(fp32)
// 256x256 tile, 8 waves (2m x 4n), BK=64 (FULL 128B cacheline per row per
// stage -> no half-line over-fetch), ring-2 LDS slots (2 x 64KB = 128KB),
// depth-1 prefetch, gate vmcnt(8) (never drains to 0 mid-loop).
// Per K-tile: 4 phases x 16 MFMA {ds_read | barrier | lgkm(0) | setprio |
// MFMA | setprio}; one end barrier per tile (reads-complete before restage).
// LDS swizzle: row R stored at R*128B; k-chunk c (8 bf16) at slot
// (c + ((R>>1)&7))&7 -> frag ds_read_b128 is 2-way per 16-lane phase (free,
// same family as the measured-0-conflict mod-4 version).
// Epilogue: u-loop INNERMOST so each quad's 4x32B of a row merge into full
// 128B lines in L2 (write-amplification fix).
// T1 bijective XCD swizzle (1152 % 8 == 0).  T5 setprio around MFMA.
// ---------------------------------------------------------------------------
__global__ __launch_bounds__(512, 2) void gemm256(
    const unsigned short* __restrict__ A,
    const unsigned short* __restrict__ Wb,
    const float* __restrict__ bias,
    unsigned short* __restrict__ C)
{
    // 2 ring slots x (A: 256x64 = 32 KB | B: 256x64 = 32 KB) = 128 KiB
    __shared__ unsigned short LdsU[2 * 32768];
    char* ldsb = (char*)LdsU;

    const int tid  = threadIdx.x;
    const int lane = tid & 63;
    const int w    = tid >> 6;        // 0..7
    const int l15  = lane & 15;
    const int quad = lane >> 4;
    const int wm   = w >> 2;          // 0..1  (m half: 128 rows)
    const int wn   = w & 3;           // 0..3  (n quarter: 64 cols)

    // T1 bijective XCD swizzle: nwg = 9*128 = 1152 = 8 * 144
    const int bid = blockIdx.y * gridDim.x + blockIdx.x;
    const int swz = (bid & 7) * 144 + (bid >> 3);
    const int n_blk = (swz % 9) * 256;
    const int m_blk = (swz / 9) * 256;

    // ---- staging addresses (full-line) ----
    // Per call c (0..3): lane covers global row R = c*64 + w*8 + (lane>>3),
    // chunk cg = ((lane&7) - rot(R)) & 7, rot(R) = (R>>1)&7 = (w*4+(lane>>4))&7
    // (c*32 vanishes mod 8).  8 lanes/row x 16B = full 128B line.
    const int rA   = w * 8 + (lane >> 3);                 // 0..63 (+c*64)
    const int rotS = (w * 4 + (lane >> 4)) & 7;
    const int cg   = ((lane & 7) - rotS) & 7;
    const unsigned short* gA = A  + (size_t)(m_blk + rA) * KDIM_ + cg * 8;
    const unsigned short* gB = Wb + (size_t)(n_blk + rA) * KDIM_ + cg * 8;
    const int dst0 = w * 1024 + lane * 16;                // c*8192 added per call

    // ---- fragment read offsets ----
    // rdA(t,kk) = (wm*128+t*16+l15)*128 + slot(kk)*16
    // rdB(u,kk) = 32768 + (wn*64+u*16+l15)*128 + slot(kk)*16
    // slot(kk) = (kk*4 + quad + (l15>>1)) & 7   (row terms vanish mod 8)
    int rowA[8], rowB[4], slot16[2];
    #pragma unroll
    for (int t = 0; t < 8; t++) rowA[t] = (wm * 128 + t * 16 + l15) * 128;
    #pragma unroll
    for (int u = 0; u < 4; u++) rowB[u] = 32768 + (wn * 64 + u * 16 + l15) * 128;
    #pragma unroll
    for (int kk = 0; kk < 2; kk++) slot16[kk] = ((kk * 4 + quad + (l15 >> 1)) & 7) * 16;

    f32x4 acc[8][4];
    #pragma unroll
    for (int t = 0; t < 8; t++)
        #pragma unroll
        for (int u = 0; u < 4; u++) acc[t][u] = (f32x4){0.f, 0.f, 0.f, 0.f};

#define STAGE(slot) do {                                                       \
    char* db_ = ldsb + (slot) * 65536;                                         \
    _Pragma("unroll")                                                          \
    for (int c_ = 0; c_ < 4; c_++) {                                           \
        __builtin_amdgcn_global_load_lds(GLOBAL_AS(gA + (size_t)c_ * (64*KDIM_)), \
            LDS_AS(db_ + c_ * 8192 + dst0), 16, 0, 0);                         \
        __builtin_amdgcn_global_load_lds(GLOBAL_AS(gB + (size_t)c_ * (64*KDIM_)), \
            LDS_AS(db_ + 32768 + c_ * 8192 + dst0), 16, 0, 0);                 \
    }                                                                          \
    gA += 64; gB += 64;                                                        \
} while (0)

#define MF4(aarr, tbase) do {                                                  \
    _Pragma("unroll")                                                          \
    for (int t_ = 0; t_ < 4; t_++)                                             \
        _Pragma("unroll")                                                      \
        for (int u_ = 0; u_ < 4; u_++)                                         \
            acc[(tbase) + t_][u_] = __builtin_amdgcn_mfma_f32_16x16x32_bf16(   \
                aarr[t_], bb[u_], acc[(tbase) + t_][u_], 0, 0, 0);             \
} while (0)

#define PH_SYNC() do {                                                         \
    asm volatile("s_barrier" ::: "memory");                                    \
    asm volatile("s_waitcnt lgkmcnt(0)" ::: "memory");                         \
    __builtin_amdgcn_sched_barrier(0);                                         \
} while (0)

// One K-tile (BK=64) from slot s: 4 phases of 16 MFMA.
#define TILE4(s) do {                                                          \
    const char* sb_ = ldsb + (s) * 65536;                                      \
    bf16x8 aa[4], bb[4];                                                       \
    /* ph0: t0-3 kk0 (+B kk0) */                                               \
    _Pragma("unroll")                                                          \
    for (int t_ = 0; t_ < 4; t_++)                                             \
        aa[t_] = *(const bf16x8*)(const void*)(sb_ + rowA[t_] + slot16[0]);    \
    _Pragma("unroll")                                                          \
    for (int u_ = 0; u_ < 4; u_++)                                             \
        bb[u_] = *(const bf16x8*)(const void*)(sb_ + rowB[u_] + slot16[0]);    \
    PH_SYNC();                                                                 \
    __builtin_amdgcn_s_setprio(1); MF4(aa, 0); __builtin_amdgcn_s_setprio(0);  \
    /* ph1: t4-7 kk0 */                                                        \
    _Pragma("unroll")                                                          \
    for (int t_ = 0; t_ < 4; t_++)                                             \
        aa[t_] = *(const bf16x8*)(const void*)(sb_ + rowA[4 + t_] + slot16[0]);\
    PH_SYNC();                                                                 \
    __builtin_amdgcn_s_setprio(1); MF4(aa, 4); __builtin_amdgcn_s_setprio(0);  \
    /* ph2: t0-3 kk1 (+B kk1) */                                               \
    _Pragma("unroll")                                                          \
    for (int t_ = 0; t_ < 4; t_++)                                             \
        aa[t_] = *(const bf16x8*)(const void*)(sb_ + rowA[t_] + slot16[1]);    \
    _Pragma("unroll")                                                          \
    for (int u_ = 0; u_ < 4; u_++)                                             \
        bb[u_] = *(const bf16x8*)(const void*)(sb_ + rowB[u_] + slot16[1]);    \
    PH_SYNC();                                                                 \
    __builtin_amdgcn_s_setprio(1); MF4(aa, 0); __builtin_amdgcn_s_setprio(0);  \
    /* ph3: t4-7 kk1 */                                                        \
    _Pragma("unroll")                                                          \
    for (int t_ = 0; t_ < 4; t_++)                                             \
        aa[t_] = *(const bf16x8*)(const void*)(sb_ + rowA[4 + t_] + slot16[1]);\
    PH_SYNC();                                                                 \
    __builtin_amdgcn_s_setprio(1); MF4(aa, 4); __builtin_amdgcn_s_setprio(0);  \
} while (0)

    // prologue: stage tile 0 into slot 0 (8 loads in flight)
    STAGE(0);

    // main: 12 K-tiles of BK=64.  Iter kt: stage kt+1 into the other slot
    // (its previous contents fully consumed — end barrier of iter kt-1),
    // then gate vmcnt(8): tile kt+1's 8 loads may stay in flight -> tile kt
    // fully landed; barrier makes it visible to all waves.
    for (int kt = 0; kt < 11; ++kt) {
        STAGE((kt + 1) & 1);
        asm volatile("s_waitcnt vmcnt(8)" ::: "memory");
        asm volatile("s_barrier" ::: "memory");
        TILE4(kt & 1);
        // end barrier: every wave's reads of this slot are COMPLETE
        // (lgkm(0) in ph3) before any wave restages it next iter.
        asm volatile("s_barrier" ::: "memory");
    }
    // tail: tile 11, no more staging
    asm volatile("s_waitcnt vmcnt(0)" ::: "memory");
    asm volatile("s_barrier" ::: "memory");
    TILE4(1);

#undef TILE4
#undef PH_SYNC
#undef MF4
#undef STAGE

    // epilogue: C[row = quad*4 + r][col = l15] per 16x16 frag (verified
    // layout).  u INNERMOST: quad's 4 x 32B per row issue back-to-back ->
    // merge into full 128B lines in L2.
    float bi[4];
    #pragma unroll
    for (int u = 0; u < 4; u++) bi[u] = bias[n_blk + wn * 64 + u * 16 + l15];
    #pragma unroll
    for (int t = 0; t < 8; t++) {
        int rbase = m_blk + wm * 128 + t * 16 + quad * 4;
        #pragma unroll
        for (int r = 0; r < 4; r++) {
            size_t rowoff = (size_t)(rbase + r) * TD_ + n_blk + wn * 64 + l15;
            #pragma unroll
            for (int u = 0; u < 4; u++)
                C[rowoff + u * 16] = f2b(acc[t][u][r] + bi[u]);
        }
    }
}

// ---------------------------------------------------------------------------
// MFMA attention. One (outer,h) per block, 4 waves, 256 threads.
// MODE 0: row attn (n=256 over L);  MODE 1: col attn (n=128 over E)
// ---------------------------------------------------------------------------
template<int MODE>
__global__ __launch_bounds__(256) void attn_mfma(
    const unsigned short* __restrict__ qkv,
    unsigned short* __restrict__ attnout,
    const int* __restrict__ mask)
{
    constexpr int N  = (MODE == 0) ? L_ : E_;
    constexpr int NT = N / 16;
    constexpr int KS = N / 32;
    constexpr int HALVES = N / 128;
    constexpr int MT = N / 64;

    __shared__ unsigned short VtS[64 * N];
    __shared__ unsigned short Ps[4][16][136];

    const int tid  = threadIdx.x;
    const int lane = tid & 63;
    const int w    = tid >> 6;
    const int quad = lane >> 4;
    const int l15  = lane & 15;
    const int hh    = blockIdx.x % H_;
    const int outer = blockIdx.x / H_;

    size_t base, stride, obase, ostride; int mbase, mstride;
    if (MODE == 0) {
        stride = TD_;              base = (size_t)outer * L_ * TD_;
        obase  = (size_t)outer * L_ * D_;  ostride = D_;
        mbase  = outer * L_;       mstride = 1;
    } else {
        stride = (size_t)L_ * TD_; base = (size_t)outer * TD_;
        obase  = (size_t)outer * D_;       ostride = (size_t)L_ * D_;
        mbase  = outer;            mstride = L_;
    }
    const unsigned short* Qg = qkv + base + hh * DH_;
    const unsigned short* Kg = Qg + D_;
    const unsigned short* Vg = Qg + 2 * D_;

    for (int c = tid; c < 4 * KS * 64; c += 256) {
        int tile = c >> 6, lc = c & 63;
        int qd = lc >> 4, fl = lc & 15;
        int dt = tile / KS, kt = tile % KS;
        int jb = kt * 32 + qd * 8;
        int d  = dt * 16 + fl;
        frag_u tmp;
        #pragma unroll
        for (int jj = 0; jj < 8; jj++)
            tmp.u[jj] = Vg[(size_t)(jb + jj) * stride + d];
        *(bf16x8*)(void*)&VtS[c * 8] = tmp.v;
    }

    float negreg[NT];
    #pragma unroll
    for (int nt = 0; nt < NT; nt++)
        negreg[nt] = mask[mbase + (nt * 16 + l15) * mstride] ? -10000.0f : 0.0f;

    __syncthreads();

    for (int mt = 0; mt < MT; mt++) {
        int m0 = (w * MT + mt) * 16;

        bf16x8 aq0 = *(const bf16x8*)(const void*)&Qg[(size_t)(m0 + l15) * stride + quad * 8];
        bf16x8 aq1 = *(const bf16x8*)(const void*)&Qg[(size_t)(m0 + l15) * stride + 32 + quad * 8];

        f32x4 sc[NT];
        #pragma unroll
        for (int nt = 0; nt < NT; nt++) sc[nt] = (f32x4){0.f,0.f,0.f,0.f};
        #pragma unroll
        for (int nt = 0; nt < NT; nt++) {
            bf16x8 bk0 = *(const bf16x8*)(const void*)&Kg[(size_t)(nt*16 + l15) * stride + quad * 8];
            bf16x8 bk1 = *(const bf16x8*)(const void*)&Kg[(size_t)(nt*16 + l15) * stride + 32 + quad * 8];
            sc[nt] = __builtin_amdgcn_mfma_f32_16x16x32_bf16(aq0, bk0, sc[nt], 0, 0, 0);
            sc[nt] = __builtin_amdgcn_mfma_f32_16x16x32_bf16(aq1, bk1, sc[nt], 0, 0, 0);
        }

        float mx[4] = {-1e30f, -1e30f, -1e30f, -1e30f};
        #pragma unroll
        for (int nt = 0; nt < NT; nt++)
            #pragma unroll
            for (int r = 0; r < 4; r++) {
                float s = sc[nt][r] * 0.125f + negreg[nt];
                sc[nt][r] = s;
                mx[r] = fmaxf(mx[r], s);
            }
        #pragma unroll
        for (int r = 0; r < 4; r++) {
            mx[r] = fmaxf(mx[r], __shfl_xor(mx[r], 1));
            mx[r] = fmaxf(mx[r], __shfl_xor(mx[r], 2));
            mx[r] = fmaxf(mx[r], __shfl_xor(mx[r], 4));
            mx[r] = fmaxf(mx[r], __shfl_xor(mx[r], 8));
        }
        float sum[4] = {0.f, 0.f, 0.f, 0.f};
        #pragma unroll
        for (int nt = 0; nt < NT; nt++)
            #pragma unroll
            for (int r = 0; r < 4; r++) {
                float p = __expf(sc[nt][r] - mx[r]);
                sc[nt][r] = p;
                sum[r] += p;
            }
        #pragma unroll
        for (int r = 0; r < 4; r++) {
            sum[r] += __shfl_xor(sum[r], 1);
            sum[r] += __shfl_xor(sum[r], 2);
            sum[r] += __shfl_xor(sum[r], 4);
            sum[r] += __shfl_xor(sum[r], 8);
        }

        f32x4 oacc[4];
        #pragma unroll
        for (int dt = 0; dt < 4; dt++) oacc[dt] = (f32x4){0.f,0.f,0.f,0.f};

        #pragma unroll
        for (int h2 = 0; h2 < HALVES; h2++) {
            #pragma unroll
            for (int t = 0; t < 8; t++)
                #pragma unroll
                for (int r = 0; r < 4; r++)
                    Ps[w][quad * 4 + r][t * 16 + l15] = f2b(sc[h2 * 8 + t][r]);
            #pragma unroll
            for (int kt = 0; kt < 4; kt++) {
                bf16x8 ap = *(const bf16x8*)(const void*)&Ps[w][l15][kt * 32 + quad * 8];
                #pragma unroll
                for (int dt = 0; dt < 4; dt++) {
                    bf16x8 bv = *(const bf16x8*)(const void*)
                        &VtS[((dt * KS + h2 * 4 + kt) * 64 + lane) * 8];
                    oacc[dt] = __builtin_amdgcn_mfma_f32_16x16x32_bf16(ap, bv, oacc[dt], 0, 0, 0);
                }
            }
        }

        float inv[4];
        #pragma unroll
        for (int r = 0; r < 4; r++) inv[r] = 1.0f / sum[r];
        #pragma unroll
        for (int dt = 0; dt < 4; dt++)
            #pragma unroll
            for (int r = 0; r < 4; r++) {
                size_t oaddr = obase + (size_t)(m0 + quad * 4 + r) * ostride
                             + hh * DH_ + dt * 16 + l15;
                attnout[oaddr] = f2b(oacc[dt][r] * inv[r]);
            }
    }
}

// ---------------------------------------------------------------------------
// out = LayerNorm(x + r) * g + beta — one wave per row.
// XBF16: residual input dtype; OBF16: output dtype.
// ---------------------------------------------------------------------------
template<int XBF16, int OBF16>
__global__ __launch_bounds__(256) void add_ln(
    const void* __restrict__ xp,
    const unsigned short* __restrict__ r,
    const float* __restrict__ g,
    const float* __restrict__ bta,
    void* __restrict__ outp)
{
    int row  = blockIdx.x * 4 + (threadIdx.x >> 6);
    int lane = threadIdx.x & 63;
    size_t off = (size_t)row * D_;
    const float* xf = (const float*)xp;
    const unsigned short* xb = (const unsigned short*)xp;
    float v[12];
    float sum = 0.f;
    #pragma unroll
    for (int j = 0; j < 12; j++) {
        int c = j * 64 + lane;
        float xv = XBF16 ? b2f(xb[off + c]) : xf[off + c];
        v[j] = xv + b2f(r[off + c]);
        sum += v[j];
    }
    for (int o = 32; o; o >>= 1) sum += __shfl_xor(sum, o);
    float mu = sum * (1.0f / 768.0f);
    float s2 = 0.f;
    #pragma unroll
    for (int j = 0; j < 12; j++) { float d = v[j] - mu; s2 = fmaf(d, d, s2); }
    for (int o = 32; o; o >>= 1) s2 += __shfl_xor(s2, o);
    float rs = rsqrtf(s2 * (1.0f / 768.0f) + 1e-5f);
    #pragma unroll
    for (int j = 0; j < 12; j++) {
        int c = j * 64 + lane;
        float y = (v[j] - mu) * rs * g[c] + bta[c];
        if (OBF16) ((unsigned short*)outp)[off + c] = f2b(y);
        else       ((float*)outp)[off + c] = y;
    }
}

// ---------------------------------------------------------------------------
extern "C" void kernel_launch(void* const* d_in, const int* in_sizes, int n_in,
                              void* d_out, int out_size, void* d_ws, size_t ws_size,
                              hipStream_t stream)
{
    const float* x     = (const float*)d_in[0];
    const float* w_row = (const float*)d_in[1];
    const float* b_row = (const float*)d_in[2];
    const float* w_col = (const float*)d_in[3];
    const float* b_col = (const float*)d_in[4];
    const float* g1    = (const float*)d_in[5];
    const float* be1   = (const float*)d_in[6];
    const float* g2    = (const float*)d_in[7];
    const float* be2   = (const float*)d_in[8];
    const int*   mask  = (const int*)d_in[9];
    float* out = (float*)d_out;

    char* ws = (char*)d_ws;
    size_t o = 0;
    unsigned short* qkv   = (unsigned short*)(ws + o); o += (size_t)M_ * TD_ * 2;    // 151 MB
    unsigned short* attn  = (unsigned short*)(ws + o); o += (size_t)M_ * D_ * 2;     // 48 MB (aliases xb)
    unsigned short* out1b = (unsigned short*)(ws + o); o += (size_t)M_ * D_ * 2;     // 48 MB
    unsigned short* wbr   = (unsigned short*)(ws + o); o += (size_t)TD_ * KDIM_ * 2; // 3.4 MB
    unsigned short* wbc   = (unsigned short*)(ws + o);                               // 3.4 MB
    unsigned short* xb    = attn;   // safe alias: xb consumed by gemm1 before attn<0> writes

    int wn4 = TD_ * KDIM_ / 4;
    int xn4 = M_ * D_ / 4;
    cvt4<<<(wn4 + 255) / 256, 256, 0, stream>>>((const float4*)w_row, (ushort4*)wbr, wn4);
    cvt4<<<(wn4 + 255) / 256, 256, 0, stream>>>((const float4*)w_col, (ushort4*)wbc, wn4);
    cvt4<<<(xn4 + 255) / 256, 256, 0, stream>>>((const float4*)x, (ushort4*)xb, xn4);

    dim3 gg(TD_ / 256, M_ / 256);   // 9 x 128 = 1152 blocks

    // ---- row attention ----
    gemm256<<<gg, 512, 0, stream>>>(xb, wbr, b_row, qkv);
    attn_mfma<0><<<E_ * H_, 256, 0, stream>>>(qkv, attn, mask);
    add_ln<0, 1><<<M_ / 4, 256, 0, stream>>>(x, attn, g1, be1, out1b);

    // ---- column attention ----
    gemm256<<<gg, 512, 0, stream>>>(out1b, wbc, b_col, qkv);
    attn_mfma<1><<<L_ * H_, 256, 0, stream>>>(qkv, attn, mask);
    add_ln<1, 0><<<M_ / 4, 256, 0, stream>>>(out1b, attn, g2, be2, out);
}